// Round 22
// baseline (248.235 us; speedup 1.0000x reference)
//
#include <hip/hip_runtime.h>

#define N_NODES 5000
#define N_EDGES 20000
#define B_GRAPHS 64
#define DD 64
#define HID 128
#define EDGE_FEAT 5
#define KTOT 8256     // 8192 + 64 bias rows (kappa')
#define NTILES 258    // real k-step tiles
#define NTILES_PAD 260
#define KY_SPLIT 8
#define KCHUNK 1032
#define GNB 16
#define S2SCAP 160

typedef unsigned short u16;
typedef float f32x4 __attribute__((ext_vector_type(4)));
typedef u16 u16x8 __attribute__((ext_vector_type(8)));
typedef __bf16 bf16x8 __attribute__((ext_vector_type(8)));
union AB { u16x8 u; bf16x8 b; };

__device__ __forceinline__ float b2f(u16 u) {
  union { unsigned u32; float f; } v; v.u32 = ((unsigned)u) << 16; return v.f;
}
__device__ __forceinline__ u16 f2b(float f) {
  union { float f; unsigned u; } v; v.f = f;
  unsigned r = v.u + 0x7FFF + ((v.u >> 16) & 1);
  return (u16)(r >> 16);
}
__device__ __forceinline__ float sigf(float x) { return 1.f / (1.f + expf(-x)); }

// -------------------- lin0: h = relu(x @ W + b), 4 nodes/block --------------------
__global__ __launch_bounds__(256) void k_lin0(const float* __restrict__ x, const float* __restrict__ w,
                       const float* __restrict__ b, float* __restrict__ h) {
  __shared__ float xs[4][64];
  int wv = threadIdx.x >> 6, j = threadIdx.x & 63;
  int n = blockIdx.x * 4 + wv;
  if (n >= N_NODES) return;
  xs[wv][j] = x[(size_t)n * 64 + j];
  __syncthreads();
  float acc = b[j];
#pragma unroll
  for (int i = 0; i < 64; ++i) acc += xs[wv][i] * w[i * 64 + j];
  h[(size_t)n * 64 + j] = fmaxf(acc, 0.f);
}

// -------------------- deg (atomic count, dst side) — fallback path only ----------
__global__ void k_deg(const int* __restrict__ dst, float* __restrict__ deg) {
  int e = blockIdx.x * 256 + threadIdx.x;
  if (e < N_EDGES) atomicAdd(&deg[dst[e]], 1.0f);
}

// -------------------- graph boundaries in sorted batch --------------------
__global__ void k_bounds(const int* __restrict__ batch, int* __restrict__ start) {
  int g = threadIdx.x;
  if (g > B_GRAPHS) return;
  int lo = 0, hi = N_NODES;
  while (lo < hi) { int mid = (lo + hi) >> 1; if (batch[mid] < g) lo = mid + 1; else hi = mid; }
  start[g] = lo;
}

// ------- r1 = relu(edge_attr @ W1 + b1), bf16 out, 2 edges/block; deg folded in -------
__global__ __launch_bounds__(256) void k_r1b(const float* __restrict__ ea, const float* __restrict__ w1,
                      const float* __restrict__ b1, u16* __restrict__ r1,
                      const int* __restrict__ dst, float* __restrict__ deg) {
  __shared__ float a[2][EDGE_FEAT];
  int t = threadIdx.x;
  int e0 = blockIdx.x * 2;
  if (t < 2 * EDGE_FEAT) a[t / EDGE_FEAT][t % EDGE_FEAT] = ea[(size_t)e0 * EDGE_FEAT + t];
  if (t >= 32 && t < 34) atomicAdd(&deg[dst[e0 + t - 32]], 1.0f);
  __syncthreads();
  int sub = t >> 7, c = t & 127;
  float acc = b1[c];
#pragma unroll
  for (int k = 0; k < EDGE_FEAT; ++k) acc += a[sub][k] * w1[k * HID + c];
  r1[(size_t)(e0 + sub) * HID + c] = f2b(fmaxf(acc, 0.f));
}

// ---------- w2tile: per-kstep 4KB tiles with fragment swizzle baked in ----------
__global__ void k_w2t2(const float* __restrict__ w2, const float* __restrict__ b2,
                       u16* __restrict__ w2tile) {
  int ks = blockIdx.x, t = threadIdx.x;
  int p0 = t * 16;
  int col = p0 >> 6;
  int rot = (p0 >> 4) & 3;
  int lkg = (rot - (col >> 1)) & 3;
  u16x8 frag;
#pragma unroll
  for (int j = 0; j < 8; ++j) {
    int kp = ks * 32 + lkg * 8 + j;
    float v = (kp < 8192) ? w2[(size_t)(kp >> 6) * 4096 + (kp & 63) * 64 + col]
                          : b2[(size_t)(kp - 8192) * 64 + col];
    frag[j] = f2b(v);
  }
  *(u16x8*)(w2tile + (size_t)ks * 2048 + t * 8) = frag;
}

// ---------- fused msg GEMM v9: 32-edge tiles (grid 1250), 2x2 wave decomposition ----------
// msg[e][o] = sum_kap rs_e(kap) * [ sum_i h[src[e]][i] * W2ext(kap,i)[o] ]
// Wave w: row-group w>>1 (16 edges), col-group w&1 (32 cols = 2 ct tiles).
__global__ __launch_bounds__(256) void k_msgf9(const int* __restrict__ src,
                                               const int* __restrict__ dst,
                                               const float* __restrict__ h,
                                               const u16* __restrict__ r1b,
                                               const u16* __restrict__ w2tile,
                                               float* __restrict__ agg) {
  __shared__ u16 r1s[32][72];
  __shared__ __align__(16) u16 Bbuf[2][8192];
  __shared__ int dsts[32];
  int bm = blockIdx.x, ky = blockIdx.y;
  int t = threadIdx.x, wave = t >> 6, lane = t & 63;
  int rowg = wave >> 1, colg = wave & 1;

  // ---- stage r1 window (64 bf16/row over 32 rows) + bias/pad slots + dsts ----
  {
    int r = t >> 3, qp = t & 7;
    int e = bm * 32 + r;
    if (t < 32) dsts[t] = (bm * 32 + t < N_EDGES) ? dst[bm * 32 + t] : -1;
    int ec = (e < N_EDGES) ? e : 0;
    *(u16x8*)&r1s[r][qp * 8] = *(const u16x8*)(r1b + (size_t)ec * HID + ky * 64 + qp * 8);
    if (qp == 0) {
      r1s[r][64] = 0x3F80;   // bf16(1.0) bias kap
#pragma unroll
      for (int z = 65; z < 72; ++z) r1s[r][z] = 0;   // zero pad kaps
    }
  }

  int row = lane & 15, lk = (lane >> 4) * 8;
  int arow = rowg * 16 + row;                       // A-supply row (of 32)
  int orow0 = rowg * 16 + ((lane >> 4) << 2);       // C/D rows orow0..orow0+3

  // ---- h fragments -> bf16 in VGPRs, converted ONCE ----
  int e_a = bm * 32 + arow;
  int se = (e_a < N_EDGES) ? src[e_a] : 0;
  const float* hp = h + (size_t)se * 64;
  f32x4 ha0 = *(const f32x4*)(hp + lk);
  f32x4 ha1 = *(const f32x4*)(hp + lk + 4);
  f32x4 hb0 = *(const f32x4*)(hp + 32 + lk);
  f32x4 hb1 = *(const f32x4*)(hp + 32 + lk + 4);
  AB hAb, hBb;
  hAb.b[0] = (__bf16)ha0.x; hAb.b[1] = (__bf16)ha0.y; hAb.b[2] = (__bf16)ha0.z; hAb.b[3] = (__bf16)ha0.w;
  hAb.b[4] = (__bf16)ha1.x; hAb.b[5] = (__bf16)ha1.y; hAb.b[6] = (__bf16)ha1.z; hAb.b[7] = (__bf16)ha1.w;
  hBb.b[0] = (__bf16)hb0.x; hBb.b[1] = (__bf16)hb0.y; hBb.b[2] = (__bf16)hb0.z; hBb.b[3] = (__bf16)hb0.w;
  hBb.b[4] = (__bf16)hb1.x; hBb.b[5] = (__bf16)hb1.y; hBb.b[6] = (__bf16)hb1.z; hBb.b[7] = (__bf16)hb1.w;

  int boff[2];
#pragma unroll
  for (int ct = 0; ct < 2; ++ct) {
    int col = colg * 32 + ct * 16 + row;
    boff[ct] = col * 32 + ((((lane >> 4) + (col >> 1)) & 3) << 3);
  }

  f32x4 acc[2];
  acc[0] = (f32x4){0.f, 0.f, 0.f, 0.f};
  acc[1] = (f32x4){0.f, 0.f, 0.f, 0.f};

  int ks0 = ky * 128;
  int nSt = ky ? 33 : 32;   // stages of 4 ksteps (2 kaps); ky1 incl bias + zero-pad tiles

  // ---- prologue: stage 0 -> buf0, load stage 1 into regs ----
  {
    size_t base = (size_t)ks0 * 2048 + t * 8;
    u16x8 q0 = *(const u16x8*)(w2tile + base);
    u16x8 q1 = *(const u16x8*)(w2tile + base + 2048);
    u16x8 q2 = *(const u16x8*)(w2tile + base + 4096);
    u16x8 q3 = *(const u16x8*)(w2tile + base + 6144);
    *(u16x8*)&Bbuf[0][t * 8] = q0;
    *(u16x8*)&Bbuf[0][2048 + t * 8] = q1;
    *(u16x8*)&Bbuf[0][4096 + t * 8] = q2;
    *(u16x8*)&Bbuf[0][6144 + t * 8] = q3;
  }
  u16x8 pv0, pv1, pv2, pv3;
  {
    size_t base = (size_t)(ks0 + 4) * 2048 + t * 8;
    pv0 = *(const u16x8*)(w2tile + base);
    pv1 = *(const u16x8*)(w2tile + base + 2048);
    pv2 = *(const u16x8*)(w2tile + base + 4096);
    pv3 = *(const u16x8*)(w2tile + base + 6144);
  }
  __syncthreads();   // buf0 + r1s + dsts ready

  for (int st = 0; st < nSt; ++st) {
    int cur = st & 1;
    if (st + 1 < nSt) {
      int nxt = cur ^ 1;
      *(u16x8*)&Bbuf[nxt][t * 8] = pv0;
      *(u16x8*)&Bbuf[nxt][2048 + t * 8] = pv1;
      *(u16x8*)&Bbuf[nxt][4096 + t * 8] = pv2;
      *(u16x8*)&Bbuf[nxt][6144 + t * 8] = pv3;
    }
    if (st + 2 < nSt) {
      size_t base = (size_t)(ks0 + (st + 2) * 4) * 2048 + t * 8;
      pv0 = *(const u16x8*)(w2tile + base);
      pv1 = *(const u16x8*)(w2tile + base + 2048);
      pv2 = *(const u16x8*)(w2tile + base + 4096);
      pv3 = *(const u16x8*)(w2tile + base + 6144);
    }
#pragma unroll
    for (int m = 0; m < 2; ++m) {
      int kapl = st * 2 + m;     // local kap index (bias=64, pads 65+)
      f32x4 rsv;
      rsv.x = b2f(r1s[orow0 + 0][kapl]);
      rsv.y = b2f(r1s[orow0 + 1][kapl]);
      rsv.z = b2f(r1s[orow0 + 2][kapl]);
      rsv.w = b2f(r1s[orow0 + 3][kapl]);
      const u16* bb0 = &Bbuf[cur][(2 * m) * 2048];       // even kstep: i in [0,32)
      const u16* bb1 = &Bbuf[cur][(2 * m + 1) * 2048];   // odd kstep: i in [32,64)
#pragma unroll
      for (int ct = 0; ct < 2; ++ct) {
        AB cb0, cb1;
        cb0.u = *(const u16x8*)(bb0 + boff[ct]);
        cb1.u = *(const u16x8*)(bb1 + boff[ct]);
        f32x4 P = __builtin_amdgcn_mfma_f32_16x16x32_bf16(hAb.b, cb0.b, (f32x4){0.f, 0.f, 0.f, 0.f}, 0, 0, 0);
        P = __builtin_amdgcn_mfma_f32_16x16x32_bf16(hBb.b, cb1.b, P, 0, 0, 0);
        acc[ct] += rsv * P;
      }
    }
    __syncthreads();   // single barrier per stage
  }

  // ---- scatter ----
#pragma unroll
  for (int ct = 0; ct < 2; ++ct) {
    int col = colg * 32 + ct * 16 + row;
#pragma unroll
    for (int r = 0; r < 4; ++r) {
      int dd = dsts[orow0 + r];
      if (dd >= 0) atomicAdd(&agg[(size_t)dd * 64 + col], acc[ct][r]);
    }
  }
}

// -------------------- fallback: fused msg (VALU; r1 recomputed in-block) ----------
__global__ __launch_bounds__(256) void k_msgv(const int* __restrict__ src,
                                              const int* __restrict__ dst,
                                              const float* __restrict__ h,
                                              const float* __restrict__ ea,
                                              const float* __restrict__ w1,
                                              const float* __restrict__ b1,
                                              const float* __restrict__ w2,
                                              const float* __restrict__ b2,
                                              float* __restrict__ agg) {
  __shared__ float hsv[64][68];
  __shared__ float r1sv[64][132];
  __shared__ float w1s[EDGE_FEAT][HID];
  __shared__ float b1s[HID];
  __shared__ float eas[64][EDGE_FEAT];
  __shared__ int dstsv[64];

  int bm = blockIdx.x, ky = blockIdx.y;
  int t = threadIdx.x;
  int wave = t >> 6, lane = t & 63;

  if (t < HID) b1s[t] = b1[t];
  for (int i = t; i < EDGE_FEAT * HID; i += 256) w1s[i / HID][i % HID] = w1[i];
  {
    int r = t >> 2, qp = t & 3;
    int e = bm * 64 + r;
    if (t < 64) dstsv[t] = (bm * 64 + t < N_EDGES) ? dst[bm * 64 + t] : -1;
    if (e < N_EDGES) {
      int s = src[e];
#pragma unroll
      for (int i = 0; i < 16; ++i) hsv[r][qp * 16 + i] = h[(size_t)s * 64 + qp * 16 + i];
      if (qp == 0)
#pragma unroll
        for (int k = 0; k < EDGE_FEAT; ++k) eas[r][k] = ea[(size_t)e * EDGE_FEAT + k];
    } else {
#pragma unroll
      for (int i = 0; i < 16; ++i) hsv[r][qp * 16 + i] = 0.f;
      if (qp == 0)
#pragma unroll
        for (int k = 0; k < EDGE_FEAT; ++k) eas[r][k] = 0.f;
    }
  }
  __syncthreads();

  for (int idx = t; idx < 64 * HID; idx += 256) {
    int rr = idx >> 7, c = idx & 127;
    float acc = b1s[c];
#pragma unroll
    for (int k = 0; k < EDGE_FEAT; ++k) acc += eas[rr][k] * w1s[k][c];
    r1sv[rr][c] = fmaxf(acc, 0.f);
  }
  if (t < 64) r1sv[t][128] = 1.0f;
  __syncthreads();

  int row0 = wave * 16 + (lane >> 4) * 4;
  int colb = lane & 15;

  float acc[4][4];
#pragma unroll
  for (int ct = 0; ct < 4; ++ct)
#pragma unroll
    for (int r = 0; r < 4; ++r) acc[ct][r] = 0.f;

  int k0 = ky * KCHUNK, k1 = k0 + KCHUNK;
  for (int kp = k0; kp < k1; ++kp) {
    int kap = kp >> 6, ii = kp & 63;
    const float* Bp = (kp < 8192) ? (w2 + (size_t)kp * 64)
                                  : (b2 + (size_t)(kp - 8192) * 64);
    float bv[4];
#pragma unroll
    for (int ct = 0; ct < 4; ++ct) bv[ct] = Bp[ct * 16 + colb];
#pragma unroll
    for (int r = 0; r < 4; ++r) {
      float a = r1sv[row0 + r][kap] * hsv[row0 + r][ii];
#pragma unroll
      for (int ct = 0; ct < 4; ++ct) acc[ct][r] += a * bv[ct];
    }
  }

#pragma unroll
  for (int ct = 0; ct < 4; ++ct) {
    int col = ct * 16 + colb;
#pragma unroll
    for (int r = 0; r < 4; ++r) {
      int dd = dstsv[row0 + r];
      if (dd >= 0) atomicAdd(&agg[(size_t)dd * 64 + col], acc[ct][r]);
    }
  }
}

// ---------- GRU step, 16 nodes/block, weights in VGPRs; zeroes agg; optional out-write ----------
__global__ __launch_bounds__(256) void k_gru2(const float* __restrict__ agg_in, const float* __restrict__ deg,
                                              const float* __restrict__ conv_b,
                                              const float* __restrict__ wih, const float* __restrict__ whh,
                                              const float* __restrict__ bih, const float* __restrict__ bhh,
                                              float* __restrict__ h, float* __restrict__ agg_clr,
                                              float* __restrict__ outp) {
  __shared__ float ms[GNB][64], hsn[GNB][64];
  __shared__ float gis[GNB][192], ghs[GNB][192];
  int n0 = blockIdx.x * GNB;
  int t = threadIdx.x;

  for (int idx = t; idx < GNB * 64; idx += 256) {
    int r = idx >> 6, c = idx & 63;
    int n = n0 + r;
    if (n < N_NODES) {
      float dg = fmaxf(deg[n], 1.0f);
      ms[r][c] = fmaxf(agg_in[(size_t)n * 64 + c] / dg + conv_b[c], 0.f);
      hsn[r][c] = h[(size_t)n * 64 + c];
      agg_clr[(size_t)n * 64 + c] = 0.f;
    } else { ms[r][c] = 0.f; hsn[r][c] = 0.f; }
  }
  __syncthreads();

  if (t < 192) {
    f32x4 wr[16];
    const f32x4* wp = (const f32x4*)(wih + (size_t)t * 64);
#pragma unroll
    for (int i = 0; i < 16; ++i) wr[i] = wp[i];
    float bi = bih[t];
    for (int n = 0; n < GNB; ++n) {
      float acc = bi;
#pragma unroll
      for (int i = 0; i < 16; ++i) {
        f32x4 v = wr[i];
        acc += ms[n][4*i] * v.x + ms[n][4*i+1] * v.y + ms[n][4*i+2] * v.z + ms[n][4*i+3] * v.w;
      }
      gis[n][t] = acc;
    }
    const f32x4* hp2 = (const f32x4*)(whh + (size_t)t * 64);
#pragma unroll
    for (int i = 0; i < 16; ++i) wr[i] = hp2[i];
    float bh = bhh[t];
    for (int n = 0; n < GNB; ++n) {
      float acc = bh;
#pragma unroll
      for (int i = 0; i < 16; ++i) {
        f32x4 v = wr[i];
        acc += hsn[n][4*i] * v.x + hsn[n][4*i+1] * v.y + hsn[n][4*i+2] * v.z + hsn[n][4*i+3] * v.w;
      }
      ghs[n][t] = acc;
    }
  }
  __syncthreads();

  for (int idx = t; idx < GNB * 64; idx += 256) {
    int rr = idx >> 6, c = idx & 63;
    int n = n0 + rr;
    if (n < N_NODES) {
      float r = sigf(gis[rr][c] + ghs[rr][c]);
      float z = sigf(gis[rr][64 + c] + ghs[rr][64 + c]);
      float nn = tanhf(gis[rr][128 + c] + r * ghs[rr][128 + c]);
      float hv = (1.f - z) * nn + z * hsn[rr][c];
      h[(size_t)n * 64 + c] = hv;
      if (outp) outp[B_GRAPHS * 128 + (size_t)n * 64 + c] = hv;
    }
  }
}

// -------------------- fused Set2Set: feat cached in LDS, 3 steps in-kernel ----------
__global__ __launch_bounds__(256) void k_s2s(const float* __restrict__ wih, const float* __restrict__ whh,
                                             const float* __restrict__ bih, const float* __restrict__ bhh,
                                             const float* __restrict__ feat, const int* __restrict__ start,
                                             float* __restrict__ ev, float* __restrict__ outq) {
  __shared__ float fl[S2SCAP][65];
  __shared__ float al[S2SCAP];
  __shared__ float qs[128], hhs[64], ccs[64], gates[256], part[4][64];
  int g = blockIdx.x, t = threadIdx.x, w = t >> 6, l = t & 63;
  int s0 = start[g], s1 = start[g + 1];
  int cnt = s1 - s0;
  bool fits = (cnt <= S2SCAP);

  if (fits) {
    for (int idx = t; idx < cnt * 16; idx += 256) {
      int n = idx >> 4, q = idx & 15;
      *(f32x4*)&fl[n][q * 4] = *(const f32x4*)(feat + (size_t)(s0 + n) * 64 + q * 4);
    }
  }
  if (t < 128) qs[t] = 0.f;
  if (t < 64) { hhs[t] = 0.f; ccs[t] = 0.f; }
  __syncthreads();

  for (int step = 0; step < 3; ++step) {
    {
      float acc = bih[t] + bhh[t];
      const f32x4* wr = (const f32x4*)(wih + (size_t)t * 128);
#pragma unroll
      for (int i = 0; i < 32; ++i) {
        f32x4 v = wr[i];
        acc += qs[4 * i] * v.x + qs[4 * i + 1] * v.y + qs[4 * i + 2] * v.z + qs[4 * i + 3] * v.w;
      }
      const f32x4* hr = (const f32x4*)(whh + (size_t)t * 64);
#pragma unroll
      for (int i = 0; i < 16; ++i) {
        f32x4 v = hr[i];
        acc += hhs[4 * i] * v.x + hhs[4 * i + 1] * v.y + hhs[4 * i + 2] * v.z + hhs[4 * i + 3] * v.w;
      }
      gates[t] = acc;
    }
    __syncthreads();
    if (t < 64) {
      float c_new = sigf(gates[64 + t]) * ccs[t] + sigf(gates[t]) * tanhf(gates[128 + t]);
      hhs[t] = sigf(gates[192 + t]) * tanhf(c_new);
      ccs[t] = c_new;
      qs[t] = hhs[t];
    }
    __syncthreads();

    float mymax = -1e30f;
    if (fits) {
      for (int n = t; n < cnt; n += 256) {
        float acc = 0.f;
#pragma unroll 16
        for (int c = 0; c < 64; ++c) acc += fl[n][c] * hhs[c];
        al[n] = acc;
        mymax = fmaxf(mymax, acc);
      }
    } else {
      for (int n = t; n < cnt; n += 256) {
        float acc = 0.f;
        for (int c = 0; c < 64; ++c) acc += feat[(size_t)(s0 + n) * 64 + c] * hhs[c];
        ev[s0 + n] = acc;
        mymax = fmaxf(mymax, acc);
      }
    }
    gates[t] = mymax; __syncthreads();
    for (int off = 128; off; off >>= 1) { if (t < off) gates[t] = fmaxf(gates[t], gates[t + off]); __syncthreads(); }
    float emax = gates[0];
    __syncthreads();

    float sd = 0.f;
    if (fits) {
      for (int n = t; n < cnt; n += 256) { float e = expf(al[n] - emax); al[n] = e; sd += e; }
    } else {
      for (int n = t; n < cnt; n += 256) sd += expf(ev[s0 + n] - emax);
    }
    gates[t] = sd; __syncthreads();
    for (int off = 128; off; off >>= 1) { if (t < off) gates[t] += gates[t + off]; __syncthreads(); }
    float den = gates[0];
    __syncthreads();

    float pacc = 0.f;
    if (fits) {
      for (int n = w; n < cnt; n += 4) pacc += al[n] * fl[n][l];
      pacc /= den;
    } else {
      for (int n = w; n < cnt; n += 4) {
        float a = expf(ev[s0 + n] - emax) / den;
        pacc += a * feat[(size_t)(s0 + n) * 64 + l];
      }
    }
    part[w][l] = pacc; __syncthreads();
    if (t < 64) qs[64 + t] = part[0][t] + part[1][t] + part[2][t] + part[3][t];
    __syncthreads();
  }
  if (t < 128) outq[g * 128 + t] = qs[t];
}

extern "C" void kernel_launch(void* const* d_in, const int* in_sizes, int n_in,
                              void* d_out, int out_size, void* d_ws, size_t ws_size,
                              hipStream_t stream) {
  (void)in_sizes; (void)n_in; (void)out_size;
  const float* x        = (const float*)d_in[0];
  const int*   ei       = (const int*)d_in[1];
  const int*   batch    = (const int*)d_in[2];
  const float* ea       = (const float*)d_in[3];
  const float* lin0_w   = (const float*)d_in[4];
  const float* lin0_b   = (const float*)d_in[5];
  const float* nn_w1    = (const float*)d_in[6];
  const float* nn_b1    = (const float*)d_in[7];
  const float* nn_w2    = (const float*)d_in[8];
  const float* nn_b2    = (const float*)d_in[9];
  const float* conv_b   = (const float*)d_in[10];
  const float* gru_w_ih = (const float*)d_in[11];
  const float* gru_w_hh = (const float*)d_in[12];
  const float* gru_b_ih = (const float*)d_in[13];
  const float* gru_b_hh = (const float*)d_in[14];
  const float* lstm_w_ih= (const float*)d_in[15];
  const float* lstm_w_hh= (const float*)d_in[16];
  const float* lstm_b_ih= (const float*)d_in[17];
  const float* lstm_b_hh= (const float*)d_in[18];
  const int* srcp = ei;
  const int* dstp = ei + N_EDGES;

  char* ws = (char*)d_ws;
  size_t off = 0;
  auto alloc = [&](size_t bytes) { void* p = ws + off; off += (bytes + 255) & ~(size_t)255; return p; };
  float* h     = (float*)alloc((size_t)N_NODES * 64 * 4);
  float* agg   = (float*)alloc((size_t)N_NODES * 64 * 4);
  float* deg   = (float*)alloc((size_t)N_NODES * 4);
  float* ev    = (float*)alloc((size_t)N_NODES * 4);
  int*   startv= (int*)alloc(65 * 4);
  u16*   r1b   = (u16*)alloc((size_t)N_EDGES * HID * 2);          // 5.12 MB
  u16*   w2tile= (u16*)alloc((size_t)NTILES_PAD * 2048 * 2);      // 1.07 MB
  bool useF = (ws_size >= off);   // ~8.8 MB total

  hipMemsetAsync(deg, 0, (size_t)N_NODES * 4, stream);
  hipMemsetAsync(agg, 0, (size_t)N_NODES * 64 * 4, stream);

  k_lin0<<<(N_NODES + 3) / 4, 256, 0, stream>>>(x, lin0_w, lin0_b, h);
  k_bounds<<<1, 128, 0, stream>>>(batch, startv);

  if (useF) {
    hipMemsetAsync(w2tile + (size_t)NTILES * 2048, 0, (size_t)(NTILES_PAD - NTILES) * 2048 * 2, stream);
    k_r1b<<<N_EDGES / 2, 256, 0, stream>>>(ea, nn_w1, nn_b1, r1b, dstp, deg);
    k_w2t2<<<NTILES, 256, 0, stream>>>(nn_w2, nn_b2, w2tile);
    for (int it = 0; it < 3; ++it) {
      k_msgf9<<<dim3(N_EDGES / 32, 2), 256, 0, stream>>>(srcp, dstp, h, r1b, w2tile, agg);
      k_gru2<<<(N_NODES + GNB - 1) / GNB, 256, 0, stream>>>(agg, deg, conv_b, gru_w_ih, gru_w_hh,
                                                            gru_b_ih, gru_b_hh, h, agg,
                                                            (it == 2) ? (float*)d_out : nullptr);
    }
  } else {
    k_deg<<<(N_EDGES + 255) / 256, 256, 0, stream>>>(dstp, deg);
    for (int it = 0; it < 3; ++it) {
      k_msgv<<<dim3(313, KY_SPLIT), 256, 0, stream>>>(srcp, dstp, h, ea, nn_w1, nn_b1,
                                                      nn_w2, nn_b2, agg);
      k_gru2<<<(N_NODES + GNB - 1) / GNB, 256, 0, stream>>>(agg, deg, conv_b, gru_w_ih, gru_w_hh,
                                                            gru_b_ih, gru_b_hh, h, agg,
                                                            (it == 2) ? (float*)d_out : nullptr);
    }
  }

  k_s2s<<<B_GRAPHS, 256, 0, stream>>>(lstm_w_ih, lstm_w_hh, lstm_b_ih, lstm_b_hh,
                                      h, startv, ev, (float*)d_out);
}

// Round 23
// 228.884 us; speedup vs baseline: 1.0845x; 1.0845x over previous
//
#include <hip/hip_runtime.h>

#define N_NODES 5000
#define N_EDGES 20000
#define B_GRAPHS 64
#define DD 64
#define HID 128
#define EDGE_FEAT 5
#define KTOT 8256     // 8192 + 64 bias rows (kappa')
#define NTILES 258    // real k-step tiles
#define NTILES_PAD 260
#define KY_SPLIT 8
#define KCHUNK 1032
#define GNB 16
#define S2SCAP 160

typedef unsigned short u16;
typedef float f32x4 __attribute__((ext_vector_type(4)));
typedef u16 u16x8 __attribute__((ext_vector_type(8)));
typedef __bf16 bf16x8 __attribute__((ext_vector_type(8)));
union AB { u16x8 u; bf16x8 b; };

__device__ __forceinline__ float b2f(u16 u) {
  union { unsigned u32; float f; } v; v.u32 = ((unsigned)u) << 16; return v.f;
}
__device__ __forceinline__ u16 f2b(float f) {
  union { float f; unsigned u; } v; v.f = f;
  unsigned r = v.u + 0x7FFF + ((v.u >> 16) & 1);
  return (u16)(r >> 16);
}
__device__ __forceinline__ float sigf(float x) { return 1.f / (1.f + expf(-x)); }

// -------------------- lin0: h = relu(x @ W + b), 4 nodes/block --------------------
__global__ __launch_bounds__(256) void k_lin0(const float* __restrict__ x, const float* __restrict__ w,
                       const float* __restrict__ b, float* __restrict__ h) {
  __shared__ float xs[4][64];
  int wv = threadIdx.x >> 6, j = threadIdx.x & 63;
  int n = blockIdx.x * 4 + wv;
  if (n >= N_NODES) return;
  xs[wv][j] = x[(size_t)n * 64 + j];
  __syncthreads();
  float acc = b[j];
#pragma unroll
  for (int i = 0; i < 64; ++i) acc += xs[wv][i] * w[i * 64 + j];
  h[(size_t)n * 64 + j] = fmaxf(acc, 0.f);
}

// -------------------- deg (atomic count, dst side) — fallback path only ----------
__global__ void k_deg(const int* __restrict__ dst, float* __restrict__ deg) {
  int e = blockIdx.x * 256 + threadIdx.x;
  if (e < N_EDGES) atomicAdd(&deg[dst[e]], 1.0f);
}

// -------------------- graph boundaries in sorted batch --------------------
__global__ void k_bounds(const int* __restrict__ batch, int* __restrict__ start) {
  int g = threadIdx.x;
  if (g > B_GRAPHS) return;
  int lo = 0, hi = N_NODES;
  while (lo < hi) { int mid = (lo + hi) >> 1; if (batch[mid] < g) lo = mid + 1; else hi = mid; }
  start[g] = lo;
}

// ------- r1 = relu(edge_attr @ W1 + b1), bf16 out, 2 edges/block; deg folded in -------
__global__ __launch_bounds__(256) void k_r1b(const float* __restrict__ ea, const float* __restrict__ w1,
                      const float* __restrict__ b1, u16* __restrict__ r1,
                      const int* __restrict__ dst, float* __restrict__ deg) {
  __shared__ float a[2][EDGE_FEAT];
  int t = threadIdx.x;
  int e0 = blockIdx.x * 2;
  if (t < 2 * EDGE_FEAT) a[t / EDGE_FEAT][t % EDGE_FEAT] = ea[(size_t)e0 * EDGE_FEAT + t];
  if (t >= 32 && t < 34) atomicAdd(&deg[dst[e0 + t - 32]], 1.0f);
  __syncthreads();
  int sub = t >> 7, c = t & 127;
  float acc = b1[c];
#pragma unroll
  for (int k = 0; k < EDGE_FEAT; ++k) acc += a[sub][k] * w1[k * HID + c];
  r1[(size_t)(e0 + sub) * HID + c] = f2b(fmaxf(acc, 0.f));
}

// ---------- w2tile: per-kstep 4KB tiles with fragment swizzle baked in ----------
// Launch NTILES_PAD blocks: ks >= NTILES writes zeros (pad tiles; no separate memset).
__global__ void k_w2t2(const float* __restrict__ w2, const float* __restrict__ b2,
                       u16* __restrict__ w2tile) {
  int ks = blockIdx.x, t = threadIdx.x;
  if (ks >= NTILES) {
    u16x8 z = (u16x8){0, 0, 0, 0, 0, 0, 0, 0};
    *(u16x8*)(w2tile + (size_t)ks * 2048 + t * 8) = z;
    return;
  }
  int p0 = t * 16;
  int col = p0 >> 6;
  int rot = (p0 >> 4) & 3;
  int lkg = (rot - (col >> 1)) & 3;
  u16x8 frag;
#pragma unroll
  for (int j = 0; j < 8; ++j) {
    int kp = ks * 32 + lkg * 8 + j;
    float v = (kp < 8192) ? w2[(size_t)(kp >> 6) * 4096 + (kp & 63) * 64 + col]
                          : b2[(size_t)(kp - 8192) * 64 + col];
    frag[j] = f2b(v);
  }
  *(u16x8*)(w2tile + (size_t)ks * 2048 + t * 8) = frag;
}

// -------------------- fused msg GEMM v4: single barrier per 4-kstep stage --------------------
// (round-17 best-measured config: ky=2, A built per-kstep, fused MFMA accumulate)
__global__ __launch_bounds__(256) void k_msgf4(const int* __restrict__ src,
                                               const int* __restrict__ dst,
                                               const float* __restrict__ h,
                                               const u16* __restrict__ r1b,
                                               const u16* __restrict__ w2tile,
                                               float* __restrict__ agg) {
  __shared__ u16 r1s[64][72];
  __shared__ __align__(16) u16 Bbuf[2][8192];
  __shared__ int dsts[64];
  int bm = blockIdx.x, ky = blockIdx.y;
  int t = threadIdx.x, wave = t >> 6, lane = t & 63;

  // ---- stage r1 window + dsts ----
  {
    int r = t >> 2, qp = t & 3;
    int e = bm * 64 + r;
    if (t < 64) dsts[t] = (bm * 64 + t < N_EDGES) ? dst[bm * 64 + t] : -1;
    int ec = (e < N_EDGES) ? e : 0;
    const u16x8* rp = (const u16x8*)(r1b + (size_t)ec * HID + ky * 64 + qp * 16);
    *(u16x8*)&r1s[r][qp * 16] = rp[0];
    *(u16x8*)&r1s[r][qp * 16 + 8] = rp[1];
    if (qp == 0) {
      r1s[r][64] = 0x3F80;
#pragma unroll
      for (int z = 65; z < 72; ++z) r1s[r][z] = 0;
    }
  }

  int row = lane & 15, lk = (lane >> 4) * 8;
  int arow = wave * 16 + row;

  // ---- h fragments straight to VGPRs ----
  int e_a = bm * 64 + arow;
  int se = (e_a < N_EDGES) ? src[e_a] : 0;
  const float* hp = h + (size_t)se * 64;
  f32x4 ha0 = *(const f32x4*)(hp + lk);
  f32x4 ha1 = *(const f32x4*)(hp + lk + 4);
  f32x4 hb0 = *(const f32x4*)(hp + 32 + lk);
  f32x4 hb1 = *(const f32x4*)(hp + 32 + lk + 4);

  int boff[4];
#pragma unroll
  for (int ct = 0; ct < 4; ++ct) {
    int col = ct * 16 + row;
    boff[ct] = col * 32 + ((((lane >> 4) + (col >> 1)) & 3) << 3);
  }

  f32x4 acc[4];
#pragma unroll
  for (int ct = 0; ct < 4; ++ct) acc[ct] = (f32x4){0.f, 0.f, 0.f, 0.f};

  int ks0 = ky * 128;
  int nSt = ky ? 33 : 32;

  // ---- prologue: stage 0 -> buf0, load stage 1 into regs ----
  {
    size_t base = (size_t)ks0 * 2048 + t * 8;
    u16x8 q0 = *(const u16x8*)(w2tile + base);
    u16x8 q1 = *(const u16x8*)(w2tile + base + 2048);
    u16x8 q2 = *(const u16x8*)(w2tile + base + 4096);
    u16x8 q3 = *(const u16x8*)(w2tile + base + 6144);
    *(u16x8*)&Bbuf[0][t * 8] = q0;
    *(u16x8*)&Bbuf[0][2048 + t * 8] = q1;
    *(u16x8*)&Bbuf[0][4096 + t * 8] = q2;
    *(u16x8*)&Bbuf[0][6144 + t * 8] = q3;
  }
  u16x8 pv0, pv1, pv2, pv3;
  {
    size_t base = (size_t)(ks0 + 4) * 2048 + t * 8;
    pv0 = *(const u16x8*)(w2tile + base);
    pv1 = *(const u16x8*)(w2tile + base + 2048);
    pv2 = *(const u16x8*)(w2tile + base + 4096);
    pv3 = *(const u16x8*)(w2tile + base + 6144);
  }
  __syncthreads();   // buf0 + r1s + dsts ready

  for (int st = 0; st < nSt; ++st) {
    int cur = st & 1;
    if (st + 1 < nSt) {     // write stage st+1 (regs) into other buffer
      int nxt = cur ^ 1;
      *(u16x8*)&Bbuf[nxt][t * 8] = pv0;
      *(u16x8*)&Bbuf[nxt][2048 + t * 8] = pv1;
      *(u16x8*)&Bbuf[nxt][4096 + t * 8] = pv2;
      *(u16x8*)&Bbuf[nxt][6144 + t * 8] = pv3;
    }
    if (st + 2 < nSt) {     // issue loads for stage st+2
      size_t base = (size_t)(ks0 + (st + 2) * 4) * 2048 + t * 8;
      pv0 = *(const u16x8*)(w2tile + base);
      pv1 = *(const u16x8*)(w2tile + base + 2048);
      pv2 = *(const u16x8*)(w2tile + base + 4096);
      pv3 = *(const u16x8*)(w2tile + base + 6144);
    }
#pragma unroll
    for (int q = 0; q < 4; ++q) {
      int s = ks0 + st * 4 + q;
      int kapl = (s >> 1) - ky * 64;
      float rs = b2f(r1s[arow][kapl]);
      f32x4 h0 = (q & 1) ? hb0 : ha0;
      f32x4 h1 = (q & 1) ? hb1 : ha1;
      AB ca;
      ca.b[0] = (__bf16)(rs * h0.x); ca.b[1] = (__bf16)(rs * h0.y);
      ca.b[2] = (__bf16)(rs * h0.z); ca.b[3] = (__bf16)(rs * h0.w);
      ca.b[4] = (__bf16)(rs * h1.x); ca.b[5] = (__bf16)(rs * h1.y);
      ca.b[6] = (__bf16)(rs * h1.z); ca.b[7] = (__bf16)(rs * h1.w);
      const u16* bb = &Bbuf[cur][q * 2048];
#pragma unroll
      for (int ct = 0; ct < 4; ++ct) {
        AB cb;
        cb.u = *(const u16x8*)(bb + boff[ct]);
        acc[ct] = __builtin_amdgcn_mfma_f32_16x16x32_bf16(ca.b, cb.b, acc[ct], 0, 0, 0);
      }
    }
    __syncthreads();   // single barrier per stage
  }

  // ---- scatter ----
  int orow0 = wave * 16 + (lane >> 4) * 4;
#pragma unroll
  for (int ct = 0; ct < 4; ++ct) {
    int col = ct * 16 + row;
#pragma unroll
    for (int r = 0; r < 4; ++r) {
      int dd = dsts[orow0 + r];
      if (dd >= 0) atomicAdd(&agg[(size_t)dd * 64 + col], acc[ct][r]);
    }
  }
}

// -------------------- fallback: fused msg (VALU; r1 recomputed in-block) ----------
__global__ __launch_bounds__(256) void k_msgv(const int* __restrict__ src,
                                              const int* __restrict__ dst,
                                              const float* __restrict__ h,
                                              const float* __restrict__ ea,
                                              const float* __restrict__ w1,
                                              const float* __restrict__ b1,
                                              const float* __restrict__ w2,
                                              const float* __restrict__ b2,
                                              float* __restrict__ agg) {
  __shared__ float hsv[64][68];
  __shared__ float r1sv[64][132];
  __shared__ float w1s[EDGE_FEAT][HID];
  __shared__ float b1s[HID];
  __shared__ float eas[64][EDGE_FEAT];
  __shared__ int dstsv[64];

  int bm = blockIdx.x, ky = blockIdx.y;
  int t = threadIdx.x;
  int wave = t >> 6, lane = t & 63;

  if (t < HID) b1s[t] = b1[t];
  for (int i = t; i < EDGE_FEAT * HID; i += 256) w1s[i / HID][i % HID] = w1[i];
  {
    int r = t >> 2, qp = t & 3;
    int e = bm * 64 + r;
    if (t < 64) dstsv[t] = (bm * 64 + t < N_EDGES) ? dst[bm * 64 + t] : -1;
    if (e < N_EDGES) {
      int s = src[e];
#pragma unroll
      for (int i = 0; i < 16; ++i) hsv[r][qp * 16 + i] = h[(size_t)s * 64 + qp * 16 + i];
      if (qp == 0)
#pragma unroll
        for (int k = 0; k < EDGE_FEAT; ++k) eas[r][k] = ea[(size_t)e * EDGE_FEAT + k];
    } else {
#pragma unroll
      for (int i = 0; i < 16; ++i) hsv[r][qp * 16 + i] = 0.f;
      if (qp == 0)
#pragma unroll
        for (int k = 0; k < EDGE_FEAT; ++k) eas[r][k] = 0.f;
    }
  }
  __syncthreads();

  for (int idx = t; idx < 64 * HID; idx += 256) {
    int rr = idx >> 7, c = idx & 127;
    float acc = b1s[c];
#pragma unroll
    for (int k = 0; k < EDGE_FEAT; ++k) acc += eas[rr][k] * w1s[k][c];
    r1sv[rr][c] = fmaxf(acc, 0.f);
  }
  if (t < 64) r1sv[t][128] = 1.0f;
  __syncthreads();

  int row0 = wave * 16 + (lane >> 4) * 4;
  int colb = lane & 15;

  float acc[4][4];
#pragma unroll
  for (int ct = 0; ct < 4; ++ct)
#pragma unroll
    for (int r = 0; r < 4; ++r) acc[ct][r] = 0.f;

  int k0 = ky * KCHUNK, k1 = k0 + KCHUNK;
  for (int kp = k0; kp < k1; ++kp) {
    int kap = kp >> 6, ii = kp & 63;
    const float* Bp = (kp < 8192) ? (w2 + (size_t)kp * 64)
                                  : (b2 + (size_t)(kp - 8192) * 64);
    float bv[4];
#pragma unroll
    for (int ct = 0; ct < 4; ++ct) bv[ct] = Bp[ct * 16 + colb];
#pragma unroll
    for (int r = 0; r < 4; ++r) {
      float a = r1sv[row0 + r][kap] * hsv[row0 + r][ii];
#pragma unroll
      for (int ct = 0; ct < 4; ++ct) acc[ct][r] += a * bv[ct];
    }
  }

#pragma unroll
  for (int ct = 0; ct < 4; ++ct) {
    int col = ct * 16 + colb;
#pragma unroll
    for (int r = 0; r < 4; ++r) {
      int dd = dstsv[row0 + r];
      if (dd >= 0) atomicAdd(&agg[(size_t)dd * 64 + col], acc[ct][r]);
    }
  }
}

// ---------- GRU step, 16 nodes/block, weights in VGPRs; zeroes agg; optional out-write ----------
__global__ __launch_bounds__(256) void k_gru2(const float* __restrict__ agg_in, const float* __restrict__ deg,
                                              const float* __restrict__ conv_b,
                                              const float* __restrict__ wih, const float* __restrict__ whh,
                                              const float* __restrict__ bih, const float* __restrict__ bhh,
                                              float* __restrict__ h, float* __restrict__ agg_clr,
                                              float* __restrict__ outp) {
  __shared__ float ms[GNB][64], hsn[GNB][64];
  __shared__ float gis[GNB][192], ghs[GNB][192];
  int n0 = blockIdx.x * GNB;
  int t = threadIdx.x;

  for (int idx = t; idx < GNB * 64; idx += 256) {
    int r = idx >> 6, c = idx & 63;
    int n = n0 + r;
    if (n < N_NODES) {
      float dg = fmaxf(deg[n], 1.0f);
      ms[r][c] = fmaxf(agg_in[(size_t)n * 64 + c] / dg + conv_b[c], 0.f);
      hsn[r][c] = h[(size_t)n * 64 + c];
      agg_clr[(size_t)n * 64 + c] = 0.f;
    } else { ms[r][c] = 0.f; hsn[r][c] = 0.f; }
  }
  __syncthreads();

  if (t < 192) {
    f32x4 wr[16];
    const f32x4* wp = (const f32x4*)(wih + (size_t)t * 64);
#pragma unroll
    for (int i = 0; i < 16; ++i) wr[i] = wp[i];
    float bi = bih[t];
    for (int n = 0; n < GNB; ++n) {
      float acc = bi;
#pragma unroll
      for (int i = 0; i < 16; ++i) {
        f32x4 v = wr[i];
        acc += ms[n][4*i] * v.x + ms[n][4*i+1] * v.y + ms[n][4*i+2] * v.z + ms[n][4*i+3] * v.w;
      }
      gis[n][t] = acc;
    }
    const f32x4* hp2 = (const f32x4*)(whh + (size_t)t * 64);
#pragma unroll
    for (int i = 0; i < 16; ++i) wr[i] = hp2[i];
    float bh = bhh[t];
    for (int n = 0; n < GNB; ++n) {
      float acc = bh;
#pragma unroll
      for (int i = 0; i < 16; ++i) {
        f32x4 v = wr[i];
        acc += hsn[n][4*i] * v.x + hsn[n][4*i+1] * v.y + hsn[n][4*i+2] * v.z + hsn[n][4*i+3] * v.w;
      }
      ghs[n][t] = acc;
    }
  }
  __syncthreads();

  for (int idx = t; idx < GNB * 64; idx += 256) {
    int rr = idx >> 6, c = idx & 63;
    int n = n0 + rr;
    if (n < N_NODES) {
      float r = sigf(gis[rr][c] + ghs[rr][c]);
      float z = sigf(gis[rr][64 + c] + ghs[rr][64 + c]);
      float nn = tanhf(gis[rr][128 + c] + r * ghs[rr][128 + c]);
      float hv = (1.f - z) * nn + z * hsn[rr][c];
      h[(size_t)n * 64 + c] = hv;
      if (outp) outp[B_GRAPHS * 128 + (size_t)n * 64 + c] = hv;
    }
  }
}

// -------------------- fused Set2Set: feat cached in LDS, 3 steps in-kernel ----------
__global__ __launch_bounds__(256) void k_s2s(const float* __restrict__ wih, const float* __restrict__ whh,
                                             const float* __restrict__ bih, const float* __restrict__ bhh,
                                             const float* __restrict__ feat, const int* __restrict__ start,
                                             float* __restrict__ ev, float* __restrict__ outq) {
  __shared__ float fl[S2SCAP][65];
  __shared__ float al[S2SCAP];
  __shared__ float qs[128], hhs[64], ccs[64], gates[256], part[4][64];
  int g = blockIdx.x, t = threadIdx.x, w = t >> 6, l = t & 63;
  int s0 = start[g], s1 = start[g + 1];
  int cnt = s1 - s0;
  bool fits = (cnt <= S2SCAP);

  if (fits) {
    for (int idx = t; idx < cnt * 16; idx += 256) {
      int n = idx >> 4, q = idx & 15;
      *(f32x4*)&fl[n][q * 4] = *(const f32x4*)(feat + (size_t)(s0 + n) * 64 + q * 4);
    }
  }
  if (t < 128) qs[t] = 0.f;
  if (t < 64) { hhs[t] = 0.f; ccs[t] = 0.f; }
  __syncthreads();

  for (int step = 0; step < 3; ++step) {
    {
      float acc = bih[t] + bhh[t];
      const f32x4* wr = (const f32x4*)(wih + (size_t)t * 128);
#pragma unroll
      for (int i = 0; i < 32; ++i) {
        f32x4 v = wr[i];
        acc += qs[4 * i] * v.x + qs[4 * i + 1] * v.y + qs[4 * i + 2] * v.z + qs[4 * i + 3] * v.w;
      }
      const f32x4* hr = (const f32x4*)(whh + (size_t)t * 64);
#pragma unroll
      for (int i = 0; i < 16; ++i) {
        f32x4 v = hr[i];
        acc += hhs[4 * i] * v.x + hhs[4 * i + 1] * v.y + hhs[4 * i + 2] * v.z + hhs[4 * i + 3] * v.w;
      }
      gates[t] = acc;
    }
    __syncthreads();
    if (t < 64) {
      float c_new = sigf(gates[64 + t]) * ccs[t] + sigf(gates[t]) * tanhf(gates[128 + t]);
      hhs[t] = sigf(gates[192 + t]) * tanhf(c_new);
      ccs[t] = c_new;
      qs[t] = hhs[t];
    }
    __syncthreads();

    float mymax = -1e30f;
    if (fits) {
      for (int n = t; n < cnt; n += 256) {
        float acc = 0.f;
#pragma unroll 16
        for (int c = 0; c < 64; ++c) acc += fl[n][c] * hhs[c];
        al[n] = acc;
        mymax = fmaxf(mymax, acc);
      }
    } else {
      for (int n = t; n < cnt; n += 256) {
        float acc = 0.f;
        for (int c = 0; c < 64; ++c) acc += feat[(size_t)(s0 + n) * 64 + c] * hhs[c];
        ev[s0 + n] = acc;
        mymax = fmaxf(mymax, acc);
      }
    }
    gates[t] = mymax; __syncthreads();
    for (int off = 128; off; off >>= 1) { if (t < off) gates[t] = fmaxf(gates[t], gates[t + off]); __syncthreads(); }
    float emax = gates[0];
    __syncthreads();

    float sd = 0.f;
    if (fits) {
      for (int n = t; n < cnt; n += 256) { float e = expf(al[n] - emax); al[n] = e; sd += e; }
    } else {
      for (int n = t; n < cnt; n += 256) sd += expf(ev[s0 + n] - emax);
    }
    gates[t] = sd; __syncthreads();
    for (int off = 128; off; off >>= 1) { if (t < off) gates[t] += gates[t + off]; __syncthreads(); }
    float den = gates[0];
    __syncthreads();

    float pacc = 0.f;
    if (fits) {
      for (int n = w; n < cnt; n += 4) pacc += al[n] * fl[n][l];
      pacc /= den;
    } else {
      for (int n = w; n < cnt; n += 4) {
        float a = expf(ev[s0 + n] - emax) / den;
        pacc += a * feat[(size_t)(s0 + n) * 64 + l];
      }
    }
    part[w][l] = pacc; __syncthreads();
    if (t < 64) qs[64 + t] = part[0][t] + part[1][t] + part[2][t] + part[3][t];
    __syncthreads();
  }
  if (t < 128) outq[g * 128 + t] = qs[t];
}

extern "C" void kernel_launch(void* const* d_in, const int* in_sizes, int n_in,
                              void* d_out, int out_size, void* d_ws, size_t ws_size,
                              hipStream_t stream) {
  (void)in_sizes; (void)n_in; (void)out_size;
  const float* x        = (const float*)d_in[0];
  const int*   ei       = (const int*)d_in[1];
  const int*   batch    = (const int*)d_in[2];
  const float* ea       = (const float*)d_in[3];
  const float* lin0_w   = (const float*)d_in[4];
  const float* lin0_b   = (const float*)d_in[5];
  const float* nn_w1    = (const float*)d_in[6];
  const float* nn_b1    = (const float*)d_in[7];
  const float* nn_w2    = (const float*)d_in[8];
  const float* nn_b2    = (const float*)d_in[9];
  const float* conv_b   = (const float*)d_in[10];
  const float* gru_w_ih = (const float*)d_in[11];
  const float* gru_w_hh = (const float*)d_in[12];
  const float* gru_b_ih = (const float*)d_in[13];
  const float* gru_b_hh = (const float*)d_in[14];
  const float* lstm_w_ih= (const float*)d_in[15];
  const float* lstm_w_hh= (const float*)d_in[16];
  const float* lstm_b_ih= (const float*)d_in[17];
  const float* lstm_b_hh= (const float*)d_in[18];
  const int* srcp = ei;
  const int* dstp = ei + N_EDGES;

  char* ws = (char*)d_ws;
  size_t off = 0;
  auto alloc = [&](size_t bytes) { void* p = ws + off; off += (bytes + 255) & ~(size_t)255; return p; };
  float* h     = (float*)alloc((size_t)N_NODES * 64 * 4);
  float* agg   = (float*)alloc((size_t)N_NODES * 64 * 4);
  float* deg   = (float*)alloc((size_t)N_NODES * 4);
  float* ev    = (float*)alloc((size_t)N_NODES * 4);
  int*   startv= (int*)alloc(65 * 4);
  u16*   r1b   = (u16*)alloc((size_t)N_EDGES * HID * 2);          // 5.12 MB
  u16*   w2tile= (u16*)alloc((size_t)NTILES_PAD * 2048 * 2);      // 1.07 MB
  bool useF = (ws_size >= off);   // ~8.8 MB total

  hipMemsetAsync(deg, 0, (size_t)N_NODES * 4, stream);
  hipMemsetAsync(agg, 0, (size_t)N_NODES * 64 * 4, stream);

  k_lin0<<<(N_NODES + 3) / 4, 256, 0, stream>>>(x, lin0_w, lin0_b, h);
  k_bounds<<<1, 128, 0, stream>>>(batch, startv);

  if (useF) {
    k_r1b<<<N_EDGES / 2, 256, 0, stream>>>(ea, nn_w1, nn_b1, r1b, dstp, deg);
    k_w2t2<<<NTILES_PAD, 256, 0, stream>>>(nn_w2, nn_b2, w2tile);
    for (int it = 0; it < 3; ++it) {
      k_msgf4<<<dim3((N_EDGES + 63) / 64, 2), 256, 0, stream>>>(srcp, dstp, h, r1b, w2tile, agg);
      k_gru2<<<(N_NODES + GNB - 1) / GNB, 256, 0, stream>>>(agg, deg, conv_b, gru_w_ih, gru_w_hh,
                                                            gru_b_ih, gru_b_hh, h, agg,
                                                            (it == 2) ? (float*)d_out : nullptr);
    }
  } else {
    k_deg<<<(N_EDGES + 255) / 256, 256, 0, stream>>>(dstp, deg);
    for (int it = 0; it < 3; ++it) {
      k_msgv<<<dim3(313, KY_SPLIT), 256, 0, stream>>>(srcp, dstp, h, ea, nn_w1, nn_b1,
                                                      nn_w2, nn_b2, agg);
      k_gru2<<<(N_NODES + GNB - 1) / GNB, 256, 0, stream>>>(agg, deg, conv_b, gru_w_ih, gru_w_hh,
                                                            gru_b_ih, gru_b_hh, h, agg,
                                                            (it == 2) ? (float*)d_out : nullptr);
    }
  }

  k_s2s<<<B_GRAPHS, 256, 0, stream>>>(lstm_w_ih, lstm_w_hh, lstm_b_ih, lstm_b_hh,
                                      h, startv, ev, (float*)d_out);
}